// Round 11
// baseline (124.535 us; speedup 1.0000x reference)
//
#include <hip/hip_runtime.h>

// TanhAttention: B=4, L=512, D=256
//   scores[b,i,j] = sum_d tanh(H[b,i,d]+H[b,j,d]) * w[d] + bias
//   alpha = softmax_j(scores); r = alpha @ H
// Outputs concatenated: r (524288 floats) then alpha (1048576 floats).
//
// Math: tanh(x) = 1 - 2/(1+e^{2x}); with E = exp2(K*h), K = 2*log2(e):
//   e^{2(hi+hj)} = Ei*Ej  ->  score_shifted = -2*sum_d w_d * rcp(fma(Ei,Ej,1))
// (softmax shift cancels sum(w)+bias -> bias unused; symmetric -> upper tiles only).
//
// R11: score frozen at R7 (best bench; its 42us resisted occupancy/LDS/trans/cache
// experiments R4-R10). Prefetch removed (R10: neutral-negative). softmax_r split:
//  - softmax_kernel: in-place row softmax, no LDS (~3us)
//  - r_gemm_kernel: output-tiled (16i x 64d) alpha@H, alpha slice in LDS (stride
//    516 = conflict-free), H traffic 268 MB -> ~64 MB L2 (the old kernel's
//    runtime was its own L2 traffic at ~20 TB/s).

#define B_ 4
#define L_ 512
#define D_ 256
#define NT16 32         // L_/16
#define NTRI16 528      // 32*33/2 upper-tri 16x16 tiles per batch
#define DT 32           // d-tile
#define NDT 8           // D_/DT
#define ST 36           // staging slot stride (dwords): conflict-free, 16B-aligned
#define SCT 20          // epilogue scratch stride

typedef float v4f __attribute__((ext_vector_type(4)));

__global__ __launch_bounds__(256) void score_kernel(
    const float* __restrict__ H, const float* __restrict__ w,
    float* __restrict__ sOut)
{
    __shared__ __align__(16) float lds[4][2][32 * ST];   // 36.9 KB; [wave][buf][slot*ST]

    const int wv   = threadIdx.x >> 6;
    const int lane = threadIdx.x & 63;
    const int tile = blockIdx.x * 4 + wv;    // 0 .. 2111
    const int b    = tile / NTRI16;
    int t = tile - b * NTRI16;
    int ti = 0;
    while (t >= NT16 - ti) { t -= NT16 - ti; ++ti; }   // wave-uniform, <=32 iters
    const int tj = ti + t;
    const int i0 = ti * 16, j0 = tj * 16;
    const float K = 2.8853900817779268f;     // 2*log2(e)
    const float* Hb = H + (size_t)b * L_ * D_;

    const int ig = lane >> 3, jg = lane & 7; // i = i0+ig+8*ii, j = j0+jg+8*jj

    // staging ownership: 32 rows (16 i + 16 j) x 8 quads = 256 quads; 4 per lane.
    int srow[4], scol[4], slot[4];
    #pragma unroll
    for (int s = 0; s < 4; ++s) {
        int idx = lane + 64 * s;
        int r = idx >> 3, q = idx & 7;
        srow[s] = (r < 16) ? (i0 + r) : (j0 + r - 16);
        scol[s] = 4 * q;
        slot[s] = r;
    }

    float* const buf[2] = { &lds[wv][0][0], &lds[wv][1][0] };

    // prologue: stage dt=0 (E = exp2(K*h))
    #pragma unroll
    for (int s = 0; s < 4; ++s) {
        float4 hv = *(const float4*)(Hb + srow[s] * D_ + scol[s]);
        v4f ev;
        ev.x = __builtin_amdgcn_exp2f(hv.x * K);
        ev.y = __builtin_amdgcn_exp2f(hv.y * K);
        ev.z = __builtin_amdgcn_exp2f(hv.z * K);
        ev.w = __builtin_amdgcn_exp2f(hv.w * K);
        *(v4f*)&buf[0][slot[s] * ST + scol[s]] = ev;
    }

    v4f acc[2][2];
    #pragma unroll
    for (int ii = 0; ii < 2; ++ii)
        #pragma unroll
        for (int jj = 0; jj < 2; ++jj) acc[ii][jj] = (v4f){0.f, 0.f, 0.f, 0.f};

    for (int dt = 0; dt < NDT; ++dt) {
        const int cur   = dt & 1;
        const bool more = (dt + 1 < NDT);
        float4 nx[4];
        if (more) {
            const int dn = (dt + 1) * DT;
            #pragma unroll
            for (int s = 0; s < 4; ++s)
                nx[s] = *(const float4*)(Hb + srow[s] * D_ + dn + scol[s]);
        }
        __builtin_amdgcn_wave_barrier();   // pin stage-writes before these reads

        #pragma unroll
        for (int q = 0; q < 8; ++q) {      // 4-d block per step
            const float4 wq = *(const float4*)(w + dt * DT + 4 * q);  // uniform -> s_load
            v4f wvv; wvv.x = wq.x; wvv.y = wq.y; wvv.z = wq.z; wvv.w = wq.w;
            v4f Ei[2], Ej[2];
            #pragma unroll
            for (int ii = 0; ii < 2; ++ii)   // slots ii*8+ig: all 32 banks once
                Ei[ii] = *(const v4f*)&buf[cur][(ii * 8 + ig) * ST + 4 * q];
            #pragma unroll
            for (int jj = 0; jj < 2; ++jj)   // slots 16+jj*8+jg: likewise
                Ej[jj] = *(const v4f*)&buf[cur][(16 + jj * 8 + jg) * ST + 4 * q];
            #pragma unroll
            for (int ii = 0; ii < 2; ++ii)
                #pragma unroll
                for (int jj = 0; jj < 2; ++jj) {
                    v4f den = Ei[ii] * Ej[jj] + 1.0f;   // fma
                    v4f rr;
                    rr.x = __builtin_amdgcn_rcpf(den.x);
                    rr.y = __builtin_amdgcn_rcpf(den.y);
                    rr.z = __builtin_amdgcn_rcpf(den.z);
                    rr.w = __builtin_amdgcn_rcpf(den.w);
                    acc[ii][jj] += wvv * rr;
                }
        }

        if (more) {
            const int nb = 1 - cur;
            #pragma unroll
            for (int s = 0; s < 4; ++s) {
                v4f ev;
                ev.x = __builtin_amdgcn_exp2f(nx[s].x * K);
                ev.y = __builtin_amdgcn_exp2f(nx[s].y * K);
                ev.z = __builtin_amdgcn_exp2f(nx[s].z * K);
                ev.w = __builtin_amdgcn_exp2f(nx[s].w * K);
                *(v4f*)&buf[nb][slot[s] * ST + scol[s]] = ev;
            }
        }
    }

    // ---- epilogue: scatter shifted scores into scratch (buf0; last reads hit buf1) ----
    float* sc = buf[0];
    __builtin_amdgcn_wave_barrier();
    #pragma unroll
    for (int ii = 0; ii < 2; ++ii)
        #pragma unroll
        for (int jj = 0; jj < 2; ++jj) {
            v4f a = acc[ii][jj];
            sc[(ig + 8 * ii) * SCT + (jg + 8 * jj)] = -2.0f * (a.x + a.y + a.z + a.w);
        }
    __builtin_amdgcn_wave_barrier();

    // upper write: 16 rows x 16 cols, b128
    {
        const int r = lane >> 2, qj = lane & 3;
        v4f val = *(const v4f*)&sc[r * SCT + 4 * qj];
        *(v4f*)&sOut[((size_t)b * L_ + i0 + r) * L_ + j0 + 4 * qj] = val;
    }
    // mirror write (off-diagonal): transposed 16x16
    if (ti != tj) {
        const int jm = lane >> 2, qi = lane & 3;
        v4f mv;
        mv.x = sc[(4 * qi + 0) * SCT + jm];
        mv.y = sc[(4 * qi + 1) * SCT + jm];
        mv.z = sc[(4 * qi + 2) * SCT + jm];
        mv.w = sc[(4 * qi + 3) * SCT + jm];
        *(v4f*)&sOut[((size_t)b * L_ + j0 + jm) * L_ + i0 + 4 * qi] = mv;
    }
}

// Phase 2a: in-place row softmax. 512 blocks x 256 thr, one wave per row.
__global__ __launch_bounds__(256) void softmax_kernel(float* __restrict__ aOut)
{
    const int tid  = threadIdx.x;
    const int blk  = blockIdx.x;     // 0..511
    const int b    = blk >> 7;
    const int i0   = (blk & 127) * 4;
    const int row  = tid >> 6;       // 0..3
    const int lane = tid & 63;
    const float L2E = 1.4426950408889634f;

    float* aRow = aOut + ((size_t)b * L_ + i0 + row) * L_;
    float v[8];
    float m = -1e30f;
    #pragma unroll
    for (int k = 0; k < 8; ++k) {
        v[k] = aRow[lane + 64 * k];      // coalesced (L2-hot scores)
        m = fmaxf(m, v[k]);
    }
    #pragma unroll
    for (int off = 1; off < 64; off <<= 1)
        m = fmaxf(m, __shfl_xor(m, off, 64));
    float s = 0.0f;
    #pragma unroll
    for (int k = 0; k < 8; ++k) {
        v[k] = __builtin_amdgcn_exp2f((v[k] - m) * L2E);
        s += v[k];
    }
    #pragma unroll
    for (int off = 1; off < 64; off <<= 1)
        s += __shfl_xor(s, off, 64);
    const float inv = __builtin_amdgcn_rcpf(s);
    #pragma unroll
    for (int k = 0; k < 8; ++k)
        aRow[lane + 64 * k] = v[k] * inv;   // overwrite scores with alpha
}

// Phase 2b: r = alpha @ H, output-tiled. Block = (b, 16 i-rows, 64 d-cols);
// grid 4*32*4 = 512. Alpha i-slice (16x512) staged in LDS (stride 516:
// (4i+j)%32 banks -> conflict-free broadcast); j-loop reads only H[:, d-tile]
// (128 KB/block -> ~64 MB total L2 traffic vs 268 MB for the fused version).
#define RSTRD 516

__global__ __launch_bounds__(256) void r_gemm_kernel(
    const float* __restrict__ H, const float* __restrict__ aOut,
    float* __restrict__ rOut)
{
    __shared__ float al[16][RSTRD];   // 33 KB

    const int tid = threadIdx.x;
    const int blk = blockIdx.x;       // 0..511
    const int b   = blk >> 7;
    const int rem = blk & 127;
    const int i0  = (rem >> 2) * 16;  // 0,16,..,496
    const int d0  = (rem & 3) * 64;   // 0,64,128,192
    const float* Hb = H + (size_t)b * L_ * D_;

    // stage alpha[i0..i0+15][0..511]: 2048 float4 / 256 thr = 8 each, coalesced
    #pragma unroll
    for (int k = 0; k < 8; ++k) {
        int idx  = tid + 256 * k;       // 0..2047
        int row  = idx >> 7;            // 0..15
        int col4 = idx & 127;
        v4f a = *(const v4f*)(aOut + ((size_t)b * L_ + i0 + row) * L_ + 4 * col4);
        *(v4f*)&al[row][4 * col4] = a;
    }
    __syncthreads();

    const int iq = tid >> 4;          // 0..15 -> i = i0 + iq
    const int dq = tid & 15;          // float4 idx -> d = d0 + 4*dq
    const v4f* H4 = (const v4f*)(Hb + d0);   // row stride 64 quads

    v4f acc = (v4f){0.f, 0.f, 0.f, 0.f};
    #pragma unroll 8
    for (int j = 0; j < L_; ++j) {
        float a = al[iq][j];                      // 4-bank spread, 16-lane broadcast
        v4f  h = H4[(size_t)j * (D_ / 4) + dq];   // 256 B/wave, L2-hot
        acc += a * h;
    }
    *(v4f*)&rOut[((size_t)b * L_ + i0 + iq) * D_ + d0 + 4 * dq] = acc;
}

extern "C" void kernel_launch(void* const* d_in, const int* in_sizes, int n_in,
                              void* d_out, int out_size, void* d_ws, size_t ws_size,
                              hipStream_t stream) {
    const float* H = (const float*)d_in[0];
    const float* w = (const float*)d_in[1];
    // d_in[2] (bias) unused: softmax shift-invariance cancels it.
    float* rOut = (float*)d_out;
    float* aOut = rOut + (size_t)B_ * L_ * D_;   // alpha region doubles as score scratch

    score_kernel<<<dim3(B_ * NTRI16 / 4), 256, 0, stream>>>(H, w, aOut);
    softmax_kernel<<<dim3(B_ * (L_ / 4)), 256, 0, stream>>>(aOut);
    r_gemm_kernel<<<dim3(B_ * 128), 256, 0, stream>>>(H, aOut, rOut);
}

// Round 12
// 88.645 us; speedup vs baseline: 1.4049x; 1.4049x over previous
//
#include <hip/hip_runtime.h>

// TanhAttention: B=4, L=512, D=256
//   scores[b,i,j] = sum_d tanh(H[b,i,d]+H[b,j,d]) * w[d] + bias
//   alpha = softmax_j(scores); r = alpha @ H
// Outputs concatenated: r (524288 floats) then alpha (1048576 floats).
//
// Math: tanh(x) = 1 - 2/(1+e^{2x}); with E = exp2(K*h), K = 2*log2(e):
//   e^{2(hi+hj)} = Ei*Ej  ->  score_shifted = -2*sum_d w_d * rcp(fma(Ei,Ej,1))
// (softmax shift cancels sum(w)+bias -> bias unused; symmetric -> upper tiles only).
//
// R12: score's 42us is invariant under occupancy/LDS/trans/cache changes; VALUBusy
// 26% => each wave ~85% stalled => T_score ~= per-wave serial latency. Attack the
// chain length: split D across the block's 4 waves (wave w owns d in [64w,64w+64),
// 2 dt iterations instead of 8 -> wave serial time /4). Total staging & math work
// unchanged; partials combined via LDS + one barrier. wq s_loads batched per dt.
// Phase 2 reverted to R7's fused softmax_r (R11's 3-kernel split regressed 23us).

#define B_ 4
#define L_ 512
#define D_ 256
#define NT16 32         // L_/16
#define NTRI16 528      // 32*33/2 upper-tri 16x16 tiles per batch
#define DT 32           // d-chunk per iteration
#define ST 36           // staging slot stride (dwords): conflict-free, 16B-aligned

typedef float v4f __attribute__((ext_vector_type(4)));

__global__ __launch_bounds__(256) void score_kernel(
    const float* __restrict__ H, const float* __restrict__ w,
    float* __restrict__ sOut)
{
    __shared__ __align__(16) float lds[4][2][32 * ST];  // 36.9 KB staging (E values)
    __shared__ float pr[4][16][17];                     // 4.35 KB partial scores
    __shared__ float sc[16][17];                        // 1.06 KB mirror transpose

    const int tid  = threadIdx.x;
    const int wv   = tid >> 6;               // D-quarter index 0..3
    const int lane = tid & 63;
    const int blk  = blockIdx.x;             // 0 .. 2111 (one block per (b,tile))
    const int b    = blk / NTRI16;
    int t = blk - b * NTRI16;
    int ti = 0;
    while (t >= NT16 - ti) { t -= NT16 - ti; ++ti; }   // uniform, <=32 iters
    const int tj = ti + t;
    const int i0 = ti * 16, j0 = tj * 16;
    const int dq0 = wv * 64;                 // this wave's D-quarter base
    const float K = 2.8853900817779268f;     // 2*log2(e)
    const float* Hb = H + (size_t)b * L_ * D_;

    const int ig = lane >> 3, jg = lane & 7; // i = i0+ig+8*ii, j = j0+jg+8*jj

    // staging: 32 rows (16 i + 16 j) x 32 d (per dt) = 256 quads; 4 per lane
    int srow[4], scol[4], slot[4];
    #pragma unroll
    for (int s = 0; s < 4; ++s) {
        int idx = lane + 64 * s;
        int r = idx >> 3, q = idx & 7;
        srow[s] = (r < 16) ? (i0 + r) : (j0 + r - 16);
        scol[s] = 4 * q;
        slot[s] = r;
    }

    float* const buf[2] = { &lds[wv][0][0], &lds[wv][1][0] };

    // prologue: stage dt=0 of this wave's quarter (E = exp2(K*h))
    #pragma unroll
    for (int s = 0; s < 4; ++s) {
        float4 hv = *(const float4*)(Hb + srow[s] * D_ + dq0 + scol[s]);
        v4f ev;
        ev.x = __builtin_amdgcn_exp2f(hv.x * K);
        ev.y = __builtin_amdgcn_exp2f(hv.y * K);
        ev.z = __builtin_amdgcn_exp2f(hv.z * K);
        ev.w = __builtin_amdgcn_exp2f(hv.w * K);
        *(v4f*)&buf[0][slot[s] * ST + scol[s]] = ev;
    }

    v4f acc[2][2];
    #pragma unroll
    for (int ii = 0; ii < 2; ++ii)
        #pragma unroll
        for (int jj = 0; jj < 2; ++jj) acc[ii][jj] = (v4f){0.f, 0.f, 0.f, 0.f};

    #pragma unroll
    for (int dt = 0; dt < 2; ++dt) {         // only 2 iterations: serial chain /4
        const int cur   = dt & 1;
        const bool more = (dt == 0);
        float4 nx[4];
        if (more) {
            #pragma unroll
            for (int s = 0; s < 4; ++s)
                nx[s] = *(const float4*)(Hb + srow[s] * D_ + dq0 + DT + scol[s]);
        }
        // batch the 8 uniform w-quads for this dt (one SMEM latency, not 8)
        float4 wqa[8];
        #pragma unroll
        for (int q = 0; q < 8; ++q)
            wqa[q] = *(const float4*)(w + dq0 + dt * DT + 4 * q);

        __builtin_amdgcn_wave_barrier();     // pin stage-writes before reads

        #pragma unroll
        for (int q = 0; q < 8; ++q) {        // 4-d block per step
            v4f wvv; wvv.x = wqa[q].x; wvv.y = wqa[q].y; wvv.z = wqa[q].z; wvv.w = wqa[q].w;
            v4f Ei[2], Ej[2];
            #pragma unroll
            for (int ii = 0; ii < 2; ++ii)   // slots ii*8+ig: all 32 banks once
                Ei[ii] = *(const v4f*)&buf[cur][(ii * 8 + ig) * ST + 4 * q];
            #pragma unroll
            for (int jj = 0; jj < 2; ++jj)
                Ej[jj] = *(const v4f*)&buf[cur][(16 + jj * 8 + jg) * ST + 4 * q];
            #pragma unroll
            for (int ii = 0; ii < 2; ++ii)
                #pragma unroll
                for (int jj = 0; jj < 2; ++jj) {
                    v4f den = Ei[ii] * Ej[jj] + 1.0f;
                    v4f rr;
                    rr.x = __builtin_amdgcn_rcpf(den.x);
                    rr.y = __builtin_amdgcn_rcpf(den.y);
                    rr.z = __builtin_amdgcn_rcpf(den.z);
                    rr.w = __builtin_amdgcn_rcpf(den.w);
                    acc[ii][jj] += wvv * rr;
                }
        }

        if (more) {
            #pragma unroll
            for (int s = 0; s < 4; ++s) {
                v4f ev;
                ev.x = __builtin_amdgcn_exp2f(nx[s].x * K);
                ev.y = __builtin_amdgcn_exp2f(nx[s].y * K);
                ev.z = __builtin_amdgcn_exp2f(nx[s].z * K);
                ev.w = __builtin_amdgcn_exp2f(nx[s].w * K);
                *(v4f*)&buf[1][slot[s] * ST + scol[s]] = ev;
            }
        }
    }

    // ---- partials to LDS: pr[wv][row][col] = this quarter's sum ----
    #pragma unroll
    for (int ii = 0; ii < 2; ++ii)
        #pragma unroll
        for (int jj = 0; jj < 2; ++jj) {
            v4f a = acc[ii][jj];
            pr[wv][ig + 8 * ii][jg + 8 * jj] = a.x + a.y + a.z + a.w;
        }
    __syncthreads();

    // ---- combine 4 quarters; each thread owns one tile element ----
    const int row = tid >> 4, col = tid & 15;
    float val = pr[0][row][col] + pr[1][row][col] + pr[2][row][col] + pr[3][row][col];
    val *= -2.0f;                                    // shifted score

    sOut[((size_t)b * L_ + i0 + row) * L_ + j0 + col] = val;   // upper, coalesced rows

    if (ti != tj) {                                  // mirror via LDS transpose
        sc[row][col] = val;
        __syncthreads();
        const int rm = tid >> 4, cm = tid & 15;
        sOut[((size_t)b * L_ + j0 + rm) * L_ + i0 + cm] = sc[cm][rm];
    }
}

// Phase 2 (R7's proven version): 512 blocks x 256 thr; 4 rows/block. Softmax in
// place, then r-phase: wave w owns j in [128w,128w+128), partial r for all 4
// rows (H[b] read once per block), LDS reduce across waves.
__global__ __launch_bounds__(256) void softmax_r_kernel(
    const float* __restrict__ H, float* __restrict__ rOut, float* __restrict__ aOut)
{
    __shared__ float sc[4][L_];      // alpha rows, 8 KB
    __shared__ float pr[4][4][D_];   // per-wave partial r, 16 KB

    const int tid  = threadIdx.x;
    const int blk  = blockIdx.x;     // 0..511
    const int b    = blk >> 7;
    const int i0   = (blk & 127) * 4;
    const int wv   = tid >> 6;       // wave 0..3
    const int lane = tid & 63;
    const float* Hb = H + (size_t)b * L_ * D_;
    const float L2E = 1.4426950408889634f;

    // ---- softmax: wave wv handles row wv ----
    {
        const int row = wv;
        float* aRow = aOut + ((size_t)b * L_ + i0 + row) * L_;
        float v[8];
        float m = -1e30f;
        #pragma unroll
        for (int k = 0; k < 8; ++k) {
            v[k] = aRow[lane + 64 * k];      // coalesced score reads (L2-hot)
            m = fmaxf(m, v[k]);
        }
        #pragma unroll
        for (int off = 1; off < 64; off <<= 1)
            m = fmaxf(m, __shfl_xor(m, off, 64));
        float s = 0.0f;
        #pragma unroll
        for (int k = 0; k < 8; ++k) {
            v[k] = __builtin_amdgcn_exp2f((v[k] - m) * L2E);
            s += v[k];
        }
        #pragma unroll
        for (int off = 1; off < 64; off <<= 1)
            s += __shfl_xor(s, off, 64);
        const float inv = __builtin_amdgcn_rcpf(s);
        #pragma unroll
        for (int k = 0; k < 8; ++k) {
            float a = v[k] * inv;
            sc[row][lane + 64 * k] = a;
            aRow[lane + 64 * k] = a;         // overwrite scores with alpha in place
        }
    }
    __syncthreads();

    // ---- r-phase: wave-cooperative over j ----
    const int jbase = 128 * wv;
    v4f racc[4];
    #pragma unroll
    for (int r = 0; r < 4; ++r) racc[r] = (v4f){0.f, 0.f, 0.f, 0.f};
    const v4f* Hb4 = (const v4f*)Hb;         // [512][64]

    for (int js = 0; js < 128; js += 4) {
        v4f av[4];
        #pragma unroll
        for (int r = 0; r < 4; ++r)
            av[r] = *(const v4f*)&sc[r][jbase + js];   // b128 uniform broadcast
        #pragma unroll
        for (int q = 0; q < 4; ++q) {
            v4f h = Hb4[(size_t)(jbase + js + q) * (D_ / 4) + lane];
            #pragma unroll
            for (int r = 0; r < 4; ++r)
                racc[r] += av[r][q] * h;
        }
    }
    #pragma unroll
    for (int r = 0; r < 4; ++r)
        *(v4f*)&pr[wv][r][4 * lane] = racc[r];
    __syncthreads();

    // ---- reduce 4 wave-partials, write r ----
    const int fq  = tid & 63;       // float4 index in D
    const int row = tid >> 6;       // 0..3
    v4f s = *(const v4f*)&pr[0][row][4 * fq];
    s += *(const v4f*)&pr[1][row][4 * fq];
    s += *(const v4f*)&pr[2][row][4 * fq];
    s += *(const v4f*)&pr[3][row][4 * fq];
    *(v4f*)&rOut[((size_t)b * L_ + i0 + row) * D_ + 4 * fq] = s;
}

extern "C" void kernel_launch(void* const* d_in, const int* in_sizes, int n_in,
                              void* d_out, int out_size, void* d_ws, size_t ws_size,
                              hipStream_t stream) {
    const float* H = (const float*)d_in[0];
    const float* w = (const float*)d_in[1];
    // d_in[2] (bias) unused: softmax shift-invariance cancels it.
    float* rOut = (float*)d_out;
    float* aOut = rOut + (size_t)B_ * L_ * D_;   // alpha region doubles as score scratch

    score_kernel<<<dim3(B_ * NTRI16), 256, 0, stream>>>(H, w, aOut);
    softmax_r_kernel<<<dim3(B_ * (L_ / 4)), 256, 0, stream>>>(H, rOut, aOut);
}

// Round 13
// 86.796 us; speedup vs baseline: 1.4348x; 1.0213x over previous
//
#include <hip/hip_runtime.h>

// TanhAttention: B=4, L=512, D=256
//   scores[b,i,j] = sum_d tanh(H[b,i,d]+H[b,j,d]) * w[d] + bias
//   alpha = softmax_j(scores); r = alpha @ H
// Outputs concatenated: r (524288 floats) then alpha (1048576 floats).
//
// Math: tanh(x) = 1 - 2/(1+e^{2x}); with E = exp2(K*h), K = 2*log2(e):
//   e^{2(hi+hj)} = Ei*Ej  ->  score_shifted = -2*sum_d w_d * rcp(fma(Ei,Ej,1))
// (softmax shift cancels sum(w)+bias -> bias unused; symmetric -> upper tiles only).
//
// R13: R12 (D split 4 ways -> chain/4) broke the 42us score plateau (bench -15us),
// confirming per-wave serial latency as the wall. Push to the limit: 8 waves/block,
// wave w owns d in [32w,32w+32) -> STRAIGHT-LINE per-wave code (one load batch,
// 16 exp2, 4 ds_write, 8 q-steps; no loop, no dbuf). 24 waves/CU resident vs 33
// total -> latency overlapped by TLP. Closed-form tile index (float sqrt) replaces
// the 32-iter while on the pre-load critical path. Phase 2 = R7 fused (proven).

#define B_ 4
#define L_ 512
#define D_ 256
#define NT16 32         // L_/16
#define NTRI16 528      // 32*33/2 upper-tri 16x16 tiles per batch
#define ST 36           // staging slot stride (dwords): conflict-free, 16B-aligned

typedef float v4f __attribute__((ext_vector_type(4)));

__global__ __launch_bounds__(512) void score_kernel(
    const float* __restrict__ H, const float* __restrict__ w,
    float* __restrict__ sOut)
{
    __shared__ __align__(16) float lds[8][32 * ST];   // 36.9 KB staging (E values)
    __shared__ float pr[8][16][17];                   // 8.7 KB partial scores
    __shared__ float sc[16][17];                      // 1.1 KB mirror transpose

    const int tid  = threadIdx.x;
    const int wv   = tid >> 6;               // D-slice index 0..7
    const int lane = tid & 63;
    const int blk  = blockIdx.x;             // 0 .. 2111 (one block per (b,tile))
    const int b    = blk / NTRI16;
    const int t    = blk - b * NTRI16;
    // closed-form upper-tri index: n = 32-ti solves n(n+1)/2 >= u, u = 528-t
    const int u  = NTRI16 - t;
    int n = (int)((__builtin_amdgcn_sqrtf((float)(8 * u + 1)) - 1.0f) * 0.5f);
    while (n * (n + 1) / 2 < u) ++n;         // fp fixup, <=2 iters
    const int ti = NT16 - n;
    const int tj = ti + (t - (NTRI16 - n * (n + 1) / 2));
    const int i0 = ti * 16, j0 = tj * 16;
    const int dq0 = wv * 32;                 // this wave's 32-d slice
    const float K = 2.8853900817779268f;     // 2*log2(e)
    const float* Hb = H + (size_t)b * L_ * D_;

    const int ig = lane >> 3, jg = lane & 7; // i = i0+ig+8*ii, j = j0+jg+8*jj

    float* const buf = &lds[wv][0];

    // ---- stage this wave's 32 rows x 32 d: 256 quads / 64 lanes = 4 each ----
    float4 hv[4];
    int slot[4], scol[4];
    #pragma unroll
    for (int s = 0; s < 4; ++s) {
        int idx = lane + 64 * s;
        int r = idx >> 3, q = idx & 7;
        int srow = (r < 16) ? (i0 + r) : (j0 + r - 16);
        slot[s] = r;
        scol[s] = 4 * q;
        hv[s] = *(const float4*)(Hb + srow * D_ + dq0 + 4 * q);   // batched loads
    }
    #pragma unroll
    for (int s = 0; s < 4; ++s) {
        v4f ev;
        ev.x = __builtin_amdgcn_exp2f(hv[s].x * K);
        ev.y = __builtin_amdgcn_exp2f(hv[s].y * K);
        ev.z = __builtin_amdgcn_exp2f(hv[s].z * K);
        ev.w = __builtin_amdgcn_exp2f(hv[s].w * K);
        *(v4f*)&buf[slot[s] * ST + scol[s]] = ev;
    }

    // batch the 8 uniform w-quads (one SMEM latency)
    float4 wqa[8];
    #pragma unroll
    for (int q = 0; q < 8; ++q)
        wqa[q] = *(const float4*)(w + dq0 + 4 * q);

    __builtin_amdgcn_wave_barrier();         // pin ds_writes before reads (own wave only)

    v4f acc[2][2];
    #pragma unroll
    for (int ii = 0; ii < 2; ++ii)
        #pragma unroll
        for (int jj = 0; jj < 2; ++jj) acc[ii][jj] = (v4f){0.f, 0.f, 0.f, 0.f};

    #pragma unroll
    for (int q = 0; q < 8; ++q) {            // 4-d block per step
        v4f wvv; wvv.x = wqa[q].x; wvv.y = wqa[q].y; wvv.z = wqa[q].z; wvv.w = wqa[q].w;
        v4f Ei[2], Ej[2];
        #pragma unroll
        for (int ii = 0; ii < 2; ++ii)       // slots ii*8+ig: all 32 banks once
            Ei[ii] = *(const v4f*)&buf[(ii * 8 + ig) * ST + 4 * q];
        #pragma unroll
        for (int jj = 0; jj < 2; ++jj)
            Ej[jj] = *(const v4f*)&buf[(16 + jj * 8 + jg) * ST + 4 * q];
        #pragma unroll
        for (int ii = 0; ii < 2; ++ii)
            #pragma unroll
            for (int jj = 0; jj < 2; ++jj) {
                v4f den = Ei[ii] * Ej[jj] + 1.0f;
                v4f rr;
                rr.x = __builtin_amdgcn_rcpf(den.x);
                rr.y = __builtin_amdgcn_rcpf(den.y);
                rr.z = __builtin_amdgcn_rcpf(den.z);
                rr.w = __builtin_amdgcn_rcpf(den.w);
                acc[ii][jj] += wvv * rr;
            }
    }

    // ---- partials to LDS ----
    #pragma unroll
    for (int ii = 0; ii < 2; ++ii)
        #pragma unroll
        for (int jj = 0; jj < 2; ++jj) {
            v4f a = acc[ii][jj];
            pr[wv][ig + 8 * ii][jg + 8 * jj] = a.x + a.y + a.z + a.w;
        }
    __syncthreads();

    // ---- combine 8 slices; threads 0..255 own one tile element each ----
    float val = 0.0f;
    const int row = (tid >> 4) & 15, col = tid & 15;
    if (tid < 256) {
        #pragma unroll
        for (int k = 0; k < 8; ++k) val += pr[k][row][col];
        val *= -2.0f;                        // shifted score
        sOut[((size_t)b * L_ + i0 + row) * L_ + j0 + col] = val;   // upper, coalesced
    }
    if (ti != tj) {                          // mirror via LDS transpose (block-uniform)
        if (tid < 256) sc[row][col] = val;
        __syncthreads();
        if (tid < 256)
            sOut[((size_t)b * L_ + j0 + row) * L_ + i0 + col] = sc[col][row];
    }
}

// Phase 2 (R7's proven version): 512 blocks x 256 thr; 4 rows/block. Softmax in
// place, then r-phase: wave w owns j in [128w,128w+128), partial r for all 4
// rows (H[b] read once per block), LDS reduce across waves.
__global__ __launch_bounds__(256) void softmax_r_kernel(
    const float* __restrict__ H, float* __restrict__ rOut, float* __restrict__ aOut)
{
    __shared__ float sc[4][L_];      // alpha rows, 8 KB
    __shared__ float pr[4][4][D_];   // per-wave partial r, 16 KB

    const int tid  = threadIdx.x;
    const int blk  = blockIdx.x;     // 0..511
    const int b    = blk >> 7;
    const int i0   = (blk & 127) * 4;
    const int wv   = tid >> 6;       // wave 0..3
    const int lane = tid & 63;
    const float* Hb = H + (size_t)b * L_ * D_;
    const float L2E = 1.4426950408889634f;

    // ---- softmax: wave wv handles row wv ----
    {
        const int row = wv;
        float* aRow = aOut + ((size_t)b * L_ + i0 + row) * L_;
        float v[8];
        float m = -1e30f;
        #pragma unroll
        for (int k = 0; k < 8; ++k) {
            v[k] = aRow[lane + 64 * k];      // coalesced score reads (L2-hot)
            m = fmaxf(m, v[k]);
        }
        #pragma unroll
        for (int off = 1; off < 64; off <<= 1)
            m = fmaxf(m, __shfl_xor(m, off, 64));
        float s = 0.0f;
        #pragma unroll
        for (int k = 0; k < 8; ++k) {
            v[k] = __builtin_amdgcn_exp2f((v[k] - m) * L2E);
            s += v[k];
        }
        #pragma unroll
        for (int off = 1; off < 64; off <<= 1)
            s += __shfl_xor(s, off, 64);
        const float inv = __builtin_amdgcn_rcpf(s);
        #pragma unroll
        for (int k = 0; k < 8; ++k) {
            float a = v[k] * inv;
            sc[row][lane + 64 * k] = a;
            aRow[lane + 64 * k] = a;         // overwrite scores with alpha in place
        }
    }
    __syncthreads();

    // ---- r-phase: wave-cooperative over j ----
    const int jbase = 128 * wv;
    v4f racc[4];
    #pragma unroll
    for (int r = 0; r < 4; ++r) racc[r] = (v4f){0.f, 0.f, 0.f, 0.f};
    const v4f* Hb4 = (const v4f*)Hb;         // [512][64]

    for (int js = 0; js < 128; js += 4) {
        v4f av[4];
        #pragma unroll
        for (int r = 0; r < 4; ++r)
            av[r] = *(const v4f*)&sc[r][jbase + js];   // b128 uniform broadcast
        #pragma unroll
        for (int q = 0; q < 4; ++q) {
            v4f h = Hb4[(size_t)(jbase + js + q) * (D_ / 4) + lane];
            #pragma unroll
            for (int r = 0; r < 4; ++r)
                racc[r] += av[r][q] * h;
        }
    }
    #pragma unroll
    for (int r = 0; r < 4; ++r)
        *(v4f*)&pr[wv][r][4 * lane] = racc[r];
    __syncthreads();

    // ---- reduce 4 wave-partials, write r ----
    const int fq  = tid & 63;       // float4 index in D
    const int row = tid >> 6;       // 0..3
    v4f s = *(const v4f*)&pr[0][row][4 * fq];
    s += *(const v4f*)&pr[1][row][4 * fq];
    s += *(const v4f*)&pr[2][row][4 * fq];
    s += *(const v4f*)&pr[3][row][4 * fq];
    *(v4f*)&rOut[((size_t)b * L_ + i0 + row) * D_ + 4 * fq] = s;
}

extern "C" void kernel_launch(void* const* d_in, const int* in_sizes, int n_in,
                              void* d_out, int out_size, void* d_ws, size_t ws_size,
                              hipStream_t stream) {
    const float* H = (const float*)d_in[0];
    const float* w = (const float*)d_in[1];
    // d_in[2] (bias) unused: softmax shift-invariance cancels it.
    float* rOut = (float*)d_out;
    float* aOut = rOut + (size_t)B_ * L_ * D_;   // alpha region doubles as score scratch

    score_kernel<<<dim3(B_ * NTRI16), 512, 0, stream>>>(H, w, aOut);
    softmax_r_kernel<<<dim3(B_ * (L_ / 4)), 256, 0, stream>>>(H, rOut, aOut);
}